// Round 2
// baseline (1015.698 us; speedup 1.0000x reference)
//
#include <hip/hip_runtime.h>

// out[b,c,w,x,v] = sum_i x[b,c,w,x,v,i] * a[b,c,i]
// B=128, C=128, X=3, Y=16 -> per (b,c): 768 rows of 16 floats (64 B), i.e.
// 3072 float4 = 48 KB of x, 16 floats of a, 768 floats (3 KB) of out.
// HBM stream: x = 805 MB read, out = 50 MB write, a = 1 MB (L2-resident).
// Roofline: 855 MB / 6.3 TB/s ~= 136 us.
//
// Structure: ONE block per (b,c). 256 threads, each thread owns a fixed
// quarter-row phase q = t&3 (so its a-quarter is loaded ONCE), and loads
// 12 float4s at stride 256 float4s -> every block-iteration is a contiguous
// 4 KB segment, every wave instruction a contiguous 1 KB segment.
// All 12 loads are issued back-to-back into registers before any use:
// 12 outstanding global_load_dwordx4 per wave hides the ~900-cycle HBM
// latency with ILP instead of relying purely on wave count.
// Quad reduce via __shfl_xor (DPP), lane q==0 stores contiguous 4 B addrs.

constexpr int YN          = 16;
constexpr int ROWS_PER_BC = 3 * YN * YN;        // 768
constexpr int F4_PER_BC   = ROWS_PER_BC * 4;    // 3072 float4 per (b,c)
constexpr int THREADS     = 256;
constexpr int ITERS       = F4_PER_BC / THREADS; // 12

__global__ __launch_bounds__(THREADS) void feat_contract_kernel(
    const float4* __restrict__ x4,
    const float*  __restrict__ na,
    float* __restrict__ out) {
    const int bc = blockIdx.x;
    const int t  = threadIdx.x;            // 0..255
    const int q  = t & 3;                  // quarter of the row (0..3), fixed

    // a quarter for this thread's phase: 4 distinct broadcast addrs per wave,
    // loaded once per thread; 1 MB array, L2-resident.
    const float4 aq = *reinterpret_cast<const float4*>(na + (size_t)bc * YN + q * 4);

    // x: block-iteration i covers float4s [i*256, i*256+256) of this bc's
    // 3072-float4 slice -> contiguous 4 KB; per wave per load: 1 KB.
    const float4* xb = x4 + (size_t)bc * F4_PER_BC + t;
    // out row for q==0 lanes: rows i*64 + (t>>2)
    float* ob = out + (size_t)bc * ROWS_PER_BC + (t >> 2);

    // Issue all 12 loads before first use -> 12 outstanding dwordx4 per wave.
    float4 v[ITERS];
#pragma unroll
    for (int i = 0; i < ITERS; ++i) v[i] = xb[i * THREADS];

#pragma unroll
    for (int i = 0; i < ITERS; ++i) {
        float s = v[i].x * aq.x + v[i].y * aq.y + v[i].z * aq.z + v[i].w * aq.w;
        // reduce across the quad (lanes t^1, t^2) — DPP quad_perm, no LDS.
        s += __shfl_xor(s, 1, 64);
        s += __shfl_xor(s, 2, 64);
        if (q == 0) {
            // active lanes 0,4,8,... store contiguous 4 B addresses.
            ob[i * 64] = s;
        }
    }
}

extern "C" void kernel_launch(void* const* d_in, const int* in_sizes, int n_in,
                              void* d_out, int out_size, void* d_ws, size_t ws_size,
                              hipStream_t stream) {
    const float4* x4 = (const float4*)d_in[0]; // [B,C,3,16,16,16] f32
    const float*  na = (const float*)d_in[1];  // [B,C,16] f32
    float* out = (float*)d_out;                // [B,C,3,16,16] f32

    const int BC = in_sizes[1] / YN;           // B*C = 16384
    dim3 grid(BC);
    dim3 block(THREADS);
    feat_contract_kernel<<<grid, block, 0, stream>>>(x4, na, out);
}